// Round 12
// baseline (11498.260 us; speedup 1.0000x reference)
//
#include <hip/hip_runtime.h>
#include <cmath>

#define TT   2048
#define EE   300
#define HH   512
#define G4H  2048     // 4*H
#define NTAG 25
#define NEGV (-10000.0f)
#define POISON 0xFFBADBADu   // NaN payload; published W*h values can never be NaN

typedef uint32_t u32x4 __attribute__((ext_vector_type(4)));

__device__ __forceinline__ float fsig(float x)  { return 1.f / (1.f + __expf(-x)); }
__device__ __forceinline__ float ftanh(float x) { return 1.f - 2.f / (__expf(2.f * x) + 1.f); }
__device__ __forceinline__ uint32_t f2u(float x) { return __float_as_uint(x); }
__device__ __forceinline__ float u2f(uint32_t x) { return __uint_as_float(x); }

// 16B write-through store (single full-quad transaction, no partial lines).
// Inline-asm STORES are safe (extra outstanding stores only make the
// compiler's counted waits conservative); asm LOADS were the r10 fault.
__device__ __forceinline__ void store16(uint32_t* p, u32x4 v) {
    asm volatile("global_store_dwordx4 %0, %1, off sc0 sc1"
                 :: "v"(p), "v"(v) : "memory");
}
// Opaque register copy: an inline-asm RESULT is not rematerializable, so the
// value must stay in a VGPR for its whole live range (r11 lesson: empty "+v"
// asm does NOT stop LLVM from re-loading the input right before the asm).
__device__ __forceinline__ float pin(float x) {
    float y;
    asm("v_mov_b32 %0, %1" : "=v"(y) : "v"(x));
    return y;
}

// ---------------- poison gates buffer (data-as-sync sentinel) ----------------
__global__ void poison_kernel(uint32_t* __restrict__ p, int n) {
    int i = blockIdx.x * blockDim.x + threadIdx.x;
    for (; i < n; i += gridDim.x * blockDim.x) p[i] = POISON;
}

// ---------------- embedding gather ----------------
__global__ void embed_kernel(const int* __restrict__ sent,
                             const float* __restrict__ emb,
                             float* __restrict__ x) {
    int t = blockIdx.x;
    int row = sent[t];
    const float4* src = (const float4*)(emb + (size_t)row * EE);
    float4* dst = (float4*)(x + (size_t)t * EE);
    for (int i = threadIdx.x; i < EE / 4; i += blockDim.x) dst[i] = src[i];
}

// ---------------- GEMM (generic, bounds-checked): C = A*B^T + b1 (+ b2) ------
#define BM 64
#define BN 64
#define BKK 16
__global__ __launch_bounds__(256)
void gemm_abt(const float* __restrict__ A, int lda,
              const float* __restrict__ B, int ldb,
              const float* __restrict__ bias1,
              const float* __restrict__ bias2,
              float* __restrict__ C, int ldc,
              int M, int N, int K) {
    __shared__ float As[BKK][BM + 4];
    __shared__ float Bs[BKK][BN + 4];
    const int tid = threadIdx.x;
    const int tx = tid & 15, ty = tid >> 4;
    const int bm = blockIdx.x * BM, bn = blockIdx.y * BN;
    float acc[4][4] = {};
    for (int k0 = 0; k0 < K; k0 += BKK) {
        #pragma unroll
        for (int i = 0; i < 4; ++i) {
            int m = (tid >> 4) + i * 16;
            int k = tid & 15;
            float a = 0.f, b = 0.f;
            if (k0 + k < K) {
                if (bm + m < M) a = A[(size_t)(bm + m) * lda + k0 + k];
                if (bn + m < N) b = B[(size_t)(bn + m) * ldb + k0 + k];
            }
            As[k][m] = a;
            Bs[k][m] = b;
        }
        __syncthreads();
        #pragma unroll
        for (int k = 0; k < BKK; ++k) {
            float4 a4 = *(const float4*)&As[k][ty * 4];
            float4 b4 = *(const float4*)&Bs[k][tx * 4];
            acc[0][0] += a4.x * b4.x; acc[0][1] += a4.x * b4.y;
            acc[0][2] += a4.x * b4.z; acc[0][3] += a4.x * b4.w;
            acc[1][0] += a4.y * b4.x; acc[1][1] += a4.y * b4.y;
            acc[1][2] += a4.y * b4.z; acc[1][3] += a4.y * b4.w;
            acc[2][0] += a4.z * b4.x; acc[2][1] += a4.z * b4.y;
            acc[2][2] += a4.z * b4.z; acc[2][3] += a4.z * b4.w;
            acc[3][0] += a4.w * b4.x; acc[3][1] += a4.w * b4.y;
            acc[3][2] += a4.w * b4.z; acc[3][3] += a4.w * b4.w;
        }
        __syncthreads();
    }
    #pragma unroll
    for (int i = 0; i < 4; ++i) {
        int m = bm + ty * 4 + i;
        if (m < M) {
            #pragma unroll
            for (int j = 0; j < 4; ++j) {
                int n = bn + tx * 4 + j;
                if (n < N) {
                    float v = acc[i][j];
                    if (bias1) v += bias1[n];
                    if (bias2) v += bias2[n];
                    C[(size_t)m * ldc + n] = v;
                }
            }
        }
    }
}

// ---------------- big GEMM (128x128 tile, 8x8/thread) ----------------
#define GM 128
#define GN 128
#define GK 16
__global__ __launch_bounds__(256)
void gemm128(const float* __restrict__ A, int lda,
             const float* __restrict__ B, int ldb,
             const float* __restrict__ bias1,
             const float* __restrict__ bias2,
             float* __restrict__ C, int ldc, int K) {
    __shared__ float As[GK][GM + 4];
    __shared__ float Bs[GK][GN + 4];
    const int tid = threadIdx.x;
    const int tx = tid & 15, ty = tid >> 4;
    const int bm = blockIdx.x * GM, bn = blockIdx.y * GN;
    const int lm = tid >> 1, lkq = (tid & 1) * 8;
    float acc[8][8] = {};
    for (int k0 = 0; k0 < K; k0 += GK) {
        float4 a0 = *(const float4*)&A[(size_t)(bm + lm) * lda + k0 + lkq];
        float4 a1 = *(const float4*)&A[(size_t)(bm + lm) * lda + k0 + lkq + 4];
        float4 b0 = *(const float4*)&B[(size_t)(bn + lm) * ldb + k0 + lkq];
        float4 b1 = *(const float4*)&B[(size_t)(bn + lm) * ldb + k0 + lkq + 4];
        As[lkq + 0][lm] = a0.x; As[lkq + 1][lm] = a0.y;
        As[lkq + 2][lm] = a0.z; As[lkq + 3][lm] = a0.w;
        As[lkq + 4][lm] = a1.x; As[lkq + 5][lm] = a1.y;
        As[lkq + 6][lm] = a1.z; As[lkq + 7][lm] = a1.w;
        Bs[lkq + 0][lm] = b0.x; Bs[lkq + 1][lm] = b0.y;
        Bs[lkq + 2][lm] = b0.z; Bs[lkq + 3][lm] = b0.w;
        Bs[lkq + 4][lm] = b1.x; Bs[lkq + 5][lm] = b1.y;
        Bs[lkq + 6][lm] = b1.z; Bs[lkq + 7][lm] = b1.w;
        __syncthreads();
        #pragma unroll
        for (int k = 0; k < GK; ++k) {
            float4 x0 = *(const float4*)&As[k][ty * 8];
            float4 x1 = *(const float4*)&As[k][ty * 8 + 4];
            float4 y0 = *(const float4*)&Bs[k][tx * 8];
            float4 y1 = *(const float4*)&Bs[k][tx * 8 + 4];
            float xa[8] = {x0.x, x0.y, x0.z, x0.w, x1.x, x1.y, x1.z, x1.w};
            float yb[8] = {y0.x, y0.y, y0.z, y0.w, y1.x, y1.y, y1.z, y1.w};
            #pragma unroll
            for (int i = 0; i < 8; ++i)
                #pragma unroll
                for (int j = 0; j < 8; ++j)
                    acc[i][j] += xa[i] * yb[j];
        }
        __syncthreads();
    }
    #pragma unroll
    for (int i = 0; i < 8; ++i) {
        int m = bm + ty * 8 + i;
        float* cr = C + (size_t)m * ldc + bn + tx * 8;
        #pragma unroll
        for (int j = 0; j < 8; ++j) {
            float v = acc[i][j];
            int n = bn + tx * 8 + j;
            if (bias1) v += bias1[n];
            if (bias2) v += bias2[n];
            cr[j] = v;
        }
    }
}

// ------ persistent BiLSTM recurrence (one dir/WG, unit-quad, v_mov-pinned w) --
// 64 WGs x 512 threads: blockIdx<32 -> fwd, >=32 -> bwd (r3 topology).
// 32-lane group g owns unit u=wg*16+g: gate rows {u,512+u,1024+u,1536+u};
// lane l covers h floats {4(l+32i)..+3}. Weights pinned via one-time opaque
// v_mov (non-remat asm result -> VGPR-resident; r3-r11 all failed to pin:
// VGPR_Count 52..96 < footprint). Poll = 4 __hip_atomic_load on one 16B quad
// (compiler-COUNTED waitcnt: gx prefetches are never drained; r11's asm poll
// with vmcnt(0) serialized them). Producer publishes raw W*h as ONE store16
// (r5: no partial-line sharing). gx pipeline 3 deep, issued after the poll.
__global__ __launch_bounds__(512, 1)
void lstm_kernel(const float* __restrict__ gx,      // [2][T][4H] input proj + biases
                 const float* __restrict__ whh_f,   // [4H][H]
                 const float* __restrict__ whh_b,   // [4H][H]
                 float* __restrict__ gates,         // [2][T][512][4] packed, poisoned
                 float* __restrict__ hout)          // [T][2H]
{
    const int tid = threadIdx.x;
    const int dir = blockIdx.x >> 5;
    const int wg  = blockIdx.x & 31;
    const int g   = tid >> 5;            // unit group 0..15
    const int l   = tid & 31;            // reduction lane
    const int u   = wg * 16 + g;         // produced unit
    const float* W = dir ? whh_b : whh_f;

    // 4 gate rows x 16 floats/lane, pinned in VGPRs via opaque v_mov
    float4 w[16];
    #pragma unroll
    for (int gb = 0; gb < 4; ++gb) {
        const float4* r = (const float4*)(W + (size_t)(gb * HH + u) * HH);
        #pragma unroll
        for (int i = 0; i < 4; ++i) {
            float4 t = r[l + 32 * i];
            w[gb * 4 + i].x = pin(t.x);
            w[gb * 4 + i].y = pin(t.y);
            w[gb * 4 + i].z = pin(t.z);
            w[gb * 4 + i].w = pin(t.w);
        }
    }

    __shared__ float h_s[2][HH];

    float c = 0.f;                       // cell state of unit `tid` (replicated per WG)
    uint32_t* gq = (uint32_t*)gates + (size_t)dir * TT * G4H;
    const float* gxd = gx + (size_t)dir * TT * G4H;

    // gx quad pipeline, 3 deep: xqC consumed this iter, xqF loaded 2 ahead
    float4 xqC{}, xqN{}, xqF{};
    {
        int t0 = dir ? TT - 1 : 0;
        int t1 = dir ? TT - 2 : 1;
        const float* q0 = gxd + (size_t)t0 * G4H + tid;
        const float* q1 = gxd + (size_t)t1 * G4H + tid;
        xqC = make_float4(q0[0], q0[HH], q0[2 * HH], q0[3 * HH]);  // A(1): act of s=1
        xqN = make_float4(q1[0], q1[HH], q1[2 * HH], q1[3 * HH]);  // A(2)
    }

    for (int s = 0; s <= TT; ++s) {
        float h = 0.f;
        if (s > 0) {
            // poll the 4 packed gates of unit `tid` (one 16B line, counted waits)
            const uint32_t* p = gq + ((size_t)(s - 1) * HH + tid) * 4;
            uint32_t v0, v1, v2, v3;
            for (;;) {
                v0 = __hip_atomic_load(p + 0, __ATOMIC_RELAXED, __HIP_MEMORY_SCOPE_AGENT);
                v1 = __hip_atomic_load(p + 1, __ATOMIC_RELAXED, __HIP_MEMORY_SCOPE_AGENT);
                v2 = __hip_atomic_load(p + 2, __ATOMIC_RELAXED, __HIP_MEMORY_SCOPE_AGENT);
                v3 = __hip_atomic_load(p + 3, __ATOMIC_RELAXED, __HIP_MEMORY_SCOPE_AGENT);
                if ((v0 != POISON) & (v1 != POISON) &
                    (v2 != POISON) & (v3 != POISON)) break;
            }
            float gi = fsig (u2f(v0) + xqC.x);
            float gf = fsig (u2f(v1) + xqC.y);
            float gg = ftanh(u2f(v2) + xqC.z);
            float go = fsig (u2f(v3) + xqC.w);
            c = gf * c + gi * gg;
            h = go * ftanh(c);
            if (wg == 0) {
                int tp = dir ? (TT - s) : (s - 1);
                hout[(size_t)tp * (2 * HH) + dir * HH + tid] = h;
            }
        }
        h_s[s & 1][tid] = h;

        // issue gx prefetch for A(s+2) AFTER the poll: never in the poll's wait
        if (s + 1 < TT) {
            int tn = dir ? (TT - 2 - s) : (s + 1);
            const float* q = gxd + (size_t)tn * G4H + tid;
            xqF = make_float4(q[0], q[HH], q[2 * HH], q[3 * HH]);
        } else {
            xqF = make_float4(0.f, 0.f, 0.f, 0.f);
        }

        if (s == TT) break;
        __syncthreads();                 // h(s) ready; dbuf covers the write side

        // dot: unit u's 4 gate rows x h_prev (4 ds_read_b128/thread)
        float a0 = 0.f, a1 = 0.f, a2 = 0.f, a3 = 0.f;
        const float4* h4 = (const float4*)h_s[s & 1];
        #pragma unroll
        for (int i = 0; i < 4; ++i) {
            float4 hv = h4[l + 32 * i];
            a0 += w[0  + i].x * hv.x + w[0  + i].y * hv.y + w[0  + i].z * hv.z + w[0  + i].w * hv.w;
            a1 += w[4  + i].x * hv.x + w[4  + i].y * hv.y + w[4  + i].z * hv.z + w[4  + i].w * hv.w;
            a2 += w[8  + i].x * hv.x + w[8  + i].y * hv.y + w[8  + i].z * hv.z + w[8  + i].w * hv.w;
            a3 += w[12 + i].x * hv.x + w[12 + i].y * hv.y + w[12 + i].z * hv.z + w[12 + i].w * hv.w;
        }
        #pragma unroll
        for (int m = 1; m <= 16; m <<= 1) {
            a0 += __shfl_xor(a0, m); a1 += __shfl_xor(a1, m);
            a2 += __shfl_xor(a2, m); a3 += __shfl_xor(a3, m);
        }
        if (l == 0) {
            u32x4 q; q.x = f2u(a0); q.y = f2u(a1); q.z = f2u(a2); q.w = f2u(a3);
            store16(gq + ((size_t)s * HH + u) * 4, q);
        }
        xqC = xqN; xqN = xqF;
    }
}

// ---------------- Viterbi forward + backtrack (bp in LDS, feats prefetch) ----
__global__ void viterbi_kernel(const float* __restrict__ feats,
                               const float* __restrict__ trans,
                               int* __restrict__ out) {
    const int n = threadIdx.x;   // blockDim = 64 (one wave)
    __shared__ float fv_s[NTAG];
    __shared__ uint8_t bp_s[TT][NTAG];   // 51200 B
    float tr[NTAG];
    if (n < NTAG) {
        #pragma unroll
        for (int p = 0; p < NTAG; ++p) tr[p] = trans[n * NTAG + p];
    }
    float fv = (n == 0) ? 0.f : NEGV;
    float fcur = (n < NTAG) ? feats[n] : 0.f;
    for (int t = 0; t < TT; ++t) {
        float fnext = (n < NTAG && t + 1 < TT) ? feats[(t + 1) * NTAG + n] : 0.f;
        if (n < NTAG) fv_s[n] = fv;
        __syncthreads();
        if (n < NTAG) {
            float best = -INFINITY; int bb = 0;
            #pragma unroll
            for (int p = 0; p < NTAG; ++p) {
                float sc = fv_s[p] + tr[p];
                if (sc > best) { best = sc; bb = p; }   // first-max tie rule
            }
            bp_s[t][n] = (uint8_t)bb;
            fv = best + fcur;
        }
        fcur = fnext;
        __syncthreads();
    }
    if (n < NTAG) fv_s[n] = fv;
    __syncthreads();
    if (n == 0) {
        float best = -INFINITY; int tag = 0;
        for (int p = 0; p < NTAG; ++p)
            if (fv_s[p] > best) { best = fv_s[p]; tag = p; }
        for (int t = TT - 1; t >= 0; --t) {
            out[t] = tag;
            tag = bp_s[t][tag];
        }
    }
}

extern "C" void kernel_launch(void* const* d_in, const int* in_sizes, int n_in,
                              void* d_out, int out_size, void* d_ws, size_t ws_size,
                              hipStream_t stream) {
    const int*   sent      = (const int*)d_in[0];
    const float* emb       = (const float*)d_in[1];
    const float* w_ih_l0_f = (const float*)d_in[2];
    const float* w_hh_l0_f = (const float*)d_in[3];
    const float* b_ih_l0_f = (const float*)d_in[4];
    const float* b_hh_l0_f = (const float*)d_in[5];
    const float* w_ih_l0_b = (const float*)d_in[6];
    const float* w_hh_l0_b = (const float*)d_in[7];
    const float* b_ih_l0_b = (const float*)d_in[8];
    const float* b_hh_l0_b = (const float*)d_in[9];
    const float* w_ih_l1_f = (const float*)d_in[10];
    const float* w_hh_l1_f = (const float*)d_in[11];
    const float* b_ih_l1_f = (const float*)d_in[12];
    const float* b_hh_l1_f = (const float*)d_in[13];
    const float* w_ih_l1_b = (const float*)d_in[14];
    const float* w_hh_l1_b = (const float*)d_in[15];
    const float* b_ih_l1_b = (const float*)d_in[16];
    const float* b_hh_l1_b = (const float*)d_in[17];
    const float* w_tag     = (const float*)d_in[18];
    const float* b_tag     = (const float*)d_in[19];
    const float* trans     = (const float*)d_in[20];

    char* ws = (char*)d_ws;
    float* x     = (float*)(ws);                 // T*300   = 2,457,600 B
    float* gx    = (float*)(ws + 2457600);       // 2*T*4H  = 33,554,432 B
    float* gates = (float*)(ws + 36012032);      // 2*T*4H  = 33,554,432 B ([2][T][512][4])
    float* h1    = (float*)(ws + 69566464);      // T*2H    = 8,388,608 B
    float* h2    = (float*)(ws + 77955072);      // T*2H    = 8,388,608 B
    float* feats = (float*)(ws + 86343680);      // T*25

    const int NGATES = 2 * TT * G4H;

    poison_kernel<<<2048, 256, 0, stream>>>((uint32_t*)gates, NGATES);

    embed_kernel<<<TT, 128, 0, stream>>>(sent, emb, x);

    dim3 g0(TT / BM, G4H / BN);
    gemm_abt<<<g0, 256, 0, stream>>>(x, EE, w_ih_l0_f, EE, b_ih_l0_f, b_hh_l0_f,
                                     gx, G4H, TT, G4H, EE);
    gemm_abt<<<g0, 256, 0, stream>>>(x, EE, w_ih_l0_b, EE, b_ih_l0_b, b_hh_l0_b,
                                     gx + (size_t)TT * G4H, G4H, TT, G4H, EE);
    lstm_kernel<<<64, 512, 0, stream>>>(gx, w_hh_l0_f, w_hh_l0_b, gates, h1);

    dim3 g1(TT / GM, G4H / GN);
    gemm128<<<g1, 256, 0, stream>>>(h1, 2 * HH, w_ih_l1_f, 2 * HH, b_ih_l1_f, b_hh_l1_f,
                                    gx, G4H, 2 * HH);
    gemm128<<<g1, 256, 0, stream>>>(h1, 2 * HH, w_ih_l1_b, 2 * HH, b_ih_l1_b, b_hh_l1_b,
                                    gx + (size_t)TT * G4H, G4H, 2 * HH);
    poison_kernel<<<2048, 256, 0, stream>>>((uint32_t*)gates, NGATES);
    lstm_kernel<<<64, 512, 0, stream>>>(gx, w_hh_l1_f, w_hh_l1_b, gates, h2);

    dim3 gf(TT / BM, 1);
    gemm_abt<<<gf, 256, 0, stream>>>(h2, 2 * HH, w_tag, 2 * HH, b_tag, nullptr,
                                     feats, NTAG, TT, NTAG, 2 * HH);

    viterbi_kernel<<<1, 64, 0, stream>>>(feats, trans, (int*)d_out);
}

// Round 13
// 7536.333 us; speedup vs baseline: 1.5257x; 1.5257x over previous
//
#include <hip/hip_runtime.h>
#include <cmath>

#define TT   2048
#define EE   300
#define HH   512
#define G4H  2048     // 4*H
#define NTAG 25
#define NEGV (-10000.0f)
#define POISON 0xFFBADBADu   // NaN payload; published gate values can never be NaN

__device__ __forceinline__ float fsig(float x)  { return 1.f / (1.f + __expf(-x)); }
__device__ __forceinline__ float ftanh(float x) { return 1.f - 2.f / (__expf(2.f * x) + 1.f); }
__device__ __forceinline__ uint32_t f2u(float x) { return __float_as_uint(x); }
__device__ __forceinline__ float u2f(uint32_t x) { return __uint_as_float(x); }

// ---------------- poison gates buffer (data-as-sync sentinel) ----------------
__global__ void poison_kernel(uint32_t* __restrict__ p, int n) {
    int i = blockIdx.x * blockDim.x + threadIdx.x;
    for (; i < n; i += gridDim.x * blockDim.x) p[i] = POISON;
}

// ---------------- embedding gather ----------------
__global__ void embed_kernel(const int* __restrict__ sent,
                             const float* __restrict__ emb,
                             float* __restrict__ x) {
    int t = blockIdx.x;
    int row = sent[t];
    const float4* src = (const float4*)(emb + (size_t)row * EE);
    float4* dst = (float4*)(x + (size_t)t * EE);
    for (int i = threadIdx.x; i < EE / 4; i += blockDim.x) dst[i] = src[i];
}

// ---------------- GEMM (generic, bounds-checked): C = A*B^T + b1 (+ b2) ------
#define BM 64
#define BN 64
#define BKK 16
__global__ __launch_bounds__(256)
void gemm_abt(const float* __restrict__ A, int lda,
              const float* __restrict__ B, int ldb,
              const float* __restrict__ bias1,
              const float* __restrict__ bias2,
              float* __restrict__ C, int ldc,
              int M, int N, int K) {
    __shared__ float As[BKK][BM + 4];
    __shared__ float Bs[BKK][BN + 4];
    const int tid = threadIdx.x;
    const int tx = tid & 15, ty = tid >> 4;
    const int bm = blockIdx.x * BM, bn = blockIdx.y * BN;
    float acc[4][4] = {};
    for (int k0 = 0; k0 < K; k0 += BKK) {
        #pragma unroll
        for (int i = 0; i < 4; ++i) {
            int m = (tid >> 4) + i * 16;
            int k = tid & 15;
            float a = 0.f, b = 0.f;
            if (k0 + k < K) {
                if (bm + m < M) a = A[(size_t)(bm + m) * lda + k0 + k];
                if (bn + m < N) b = B[(size_t)(bn + m) * ldb + k0 + k];
            }
            As[k][m] = a;
            Bs[k][m] = b;
        }
        __syncthreads();
        #pragma unroll
        for (int k = 0; k < BKK; ++k) {
            float4 a4 = *(const float4*)&As[k][ty * 4];
            float4 b4 = *(const float4*)&Bs[k][tx * 4];
            acc[0][0] += a4.x * b4.x; acc[0][1] += a4.x * b4.y;
            acc[0][2] += a4.x * b4.z; acc[0][3] += a4.x * b4.w;
            acc[1][0] += a4.y * b4.x; acc[1][1] += a4.y * b4.y;
            acc[1][2] += a4.y * b4.z; acc[1][3] += a4.y * b4.w;
            acc[2][0] += a4.z * b4.x; acc[2][1] += a4.z * b4.y;
            acc[2][2] += a4.z * b4.z; acc[2][3] += a4.z * b4.w;
            acc[3][0] += a4.w * b4.x; acc[3][1] += a4.w * b4.y;
            acc[3][2] += a4.w * b4.z; acc[3][3] += a4.w * b4.w;
        }
        __syncthreads();
    }
    #pragma unroll
    for (int i = 0; i < 4; ++i) {
        int m = bm + ty * 4 + i;
        if (m < M) {
            #pragma unroll
            for (int j = 0; j < 4; ++j) {
                int n = bn + tx * 4 + j;
                if (n < N) {
                    float v = acc[i][j];
                    if (bias1) v += bias1[n];
                    if (bias2) v += bias2[n];
                    C[(size_t)m * ldc + n] = v;
                }
            }
        }
    }
}

// ---------------- big GEMM (128x128 tile, 8x8/thread) ----------------
#define GM 128
#define GN 128
#define GK 16
__global__ __launch_bounds__(256)
void gemm128(const float* __restrict__ A, int lda,
             const float* __restrict__ B, int ldb,
             const float* __restrict__ bias1,
             const float* __restrict__ bias2,
             float* __restrict__ C, int ldc, int K) {
    __shared__ float As[GK][GM + 4];
    __shared__ float Bs[GK][GN + 4];
    const int tid = threadIdx.x;
    const int tx = tid & 15, ty = tid >> 4;
    const int bm = blockIdx.x * GM, bn = blockIdx.y * GN;
    const int lm = tid >> 1, lkq = (tid & 1) * 8;
    float acc[8][8] = {};
    for (int k0 = 0; k0 < K; k0 += GK) {
        float4 a0 = *(const float4*)&A[(size_t)(bm + lm) * lda + k0 + lkq];
        float4 a1 = *(const float4*)&A[(size_t)(bm + lm) * lda + k0 + lkq + 4];
        float4 b0 = *(const float4*)&B[(size_t)(bn + lm) * ldb + k0 + lkq];
        float4 b1 = *(const float4*)&B[(size_t)(bn + lm) * ldb + k0 + lkq + 4];
        As[lkq + 0][lm] = a0.x; As[lkq + 1][lm] = a0.y;
        As[lkq + 2][lm] = a0.z; As[lkq + 3][lm] = a0.w;
        As[lkq + 4][lm] = a1.x; As[lkq + 5][lm] = a1.y;
        As[lkq + 6][lm] = a1.z; As[lkq + 7][lm] = a1.w;
        Bs[lkq + 0][lm] = b0.x; Bs[lkq + 1][lm] = b0.y;
        Bs[lkq + 2][lm] = b0.z; Bs[lkq + 3][lm] = b0.w;
        Bs[lkq + 4][lm] = b1.x; Bs[lkq + 5][lm] = b1.y;
        Bs[lkq + 6][lm] = b1.z; Bs[lkq + 7][lm] = b1.w;
        __syncthreads();
        #pragma unroll
        for (int k = 0; k < GK; ++k) {
            float4 x0 = *(const float4*)&As[k][ty * 8];
            float4 x1 = *(const float4*)&As[k][ty * 8 + 4];
            float4 y0 = *(const float4*)&Bs[k][tx * 8];
            float4 y1 = *(const float4*)&Bs[k][tx * 8 + 4];
            float xa[8] = {x0.x, x0.y, x0.z, x0.w, x1.x, x1.y, x1.z, x1.w};
            float yb[8] = {y0.x, y0.y, y0.z, y0.w, y1.x, y1.y, y1.z, y1.w};
            #pragma unroll
            for (int i = 0; i < 8; ++i)
                #pragma unroll
                for (int j = 0; j < 8; ++j)
                    acc[i][j] += xa[i] * yb[j];
        }
        __syncthreads();
    }
    #pragma unroll
    for (int i = 0; i < 8; ++i) {
        int m = bm + ty * 8 + i;
        float* cr = C + (size_t)m * ldc + bn + tx * 8;
        #pragma unroll
        for (int j = 0; j < 8; ++j) {
            float v = acc[i][j];
            int n = bn + tx * 8 + j;
            if (bias1) v += bias1[n];
            if (bias2) v += bias2[n];
            cr[j] = v;
        }
    }
}

// ------- persistent BiLSTM recurrence: r3 structure + VOLATILE self-mov pin ---
// 64 WGs x 512 threads: blockIdx<32 -> fwd, >=32 -> bwd. This is EXACTLY the
// round-3 kernel (best measured: 3110 us/layer) with one change: the weights
// are pinned by `asm volatile("v_mov_b32 %0,%0":"+v")` — volatile asm executes
// exactly once, cannot be sunk/duplicated, and its result cannot be remat'd,
// so the 64 weight floats MUST stay VGPR-resident.
// Pin-attempt ledger: r3/r9 pre-loop empty asm -> sunk (VGPR 52/96);
// r10 volatile asm LOADS -> fault (no internal waitcnt); r11 loop-carried
// empty "+v" -> reloaded each iter (VGPR 68); r12 non-volatile mov -> sunk
// (VGPR 56). Success signature this round: VGPR_Count >= ~120.
__global__ __launch_bounds__(512, 1)
void lstm_kernel(const float* __restrict__ gx,      // [2][T][4H] input proj + biases
                 const float* __restrict__ whh_f,   // [4H][H]
                 const float* __restrict__ whh_b,   // [4H][H]
                 float* __restrict__ gates,         // [2][T][4H] poisoned
                 float* __restrict__ hout)          // [T][2H]
{
    const int tid = threadIdx.x;
    const int dir = blockIdx.x >> 5;
    const int wg  = blockIdx.x & 31;
    const int r   = tid >> 3;        // 0..63 gate row within WG
    const int cch = tid & 7;         // k-chunk lane
    const int gb  = r >> 4;          // gate block: 0=i 1=f 2=g 3=o
    const int ur  = r & 15;          // unit within WG
    const int grow = gb * HH + wg * 16 + ur;   // global gate row
    const float* W = dir ? whh_b : whh_f;

    // 64 recurrent weights/thread, strided float4s (conflict-free vs h_s reads)
    float4 w[16];
    {
        const float4* wr = (const float4*)(W + (size_t)grow * HH);
        #pragma unroll
        for (int i = 0; i < 16; ++i) w[i] = wr[cch + 8 * i];
    }
    // VOLATILE pin: executes once, result non-rematerializable -> VGPR-resident
    #pragma unroll
    for (int i = 0; i < 16; ++i) {
        asm volatile("v_mov_b32 %0, %0" : "+v"(w[i].x));
        asm volatile("v_mov_b32 %0, %0" : "+v"(w[i].y));
        asm volatile("v_mov_b32 %0, %0" : "+v"(w[i].z));
        asm volatile("v_mov_b32 %0, %0" : "+v"(w[i].w));
    }

    __shared__ float h_s[HH];

    float c = 0.f;                         // cell state of unit `tid` (replicated per WG)
    uint32_t* gbuf = (uint32_t*)(gates + (size_t)dir * TT * G4H);
    const float* gxd = gx + (size_t)dir * TT * G4H;

    // gx prefetch pipeline, 2 steps deep (cch==0 lanes only)
    float gxc = 0.f, gxn = 0.f, gxf = 0.f;
    if (cch == 0) {
        int t0 = dir ? TT - 1 : 0;
        int t1 = dir ? TT - 2 : 1;
        gxc = gxd[(size_t)t0 * G4H + grow];
        gxn = gxd[(size_t)t1 * G4H + grow];
    }

    for (int s = 0; s <= TT; ++s) {
        if (s > 0) {
            // poll this unit's 4 gate words from step s-1 (4 loads in flight)
            const uint32_t* gp = gbuf + (size_t)(s - 1) * G4H + tid;
            uint32_t v0, v1, v2, v3;
            for (;;) {
                v0 = __hip_atomic_load(gp,        __ATOMIC_RELAXED, __HIP_MEMORY_SCOPE_AGENT);
                v1 = __hip_atomic_load(gp + 512,  __ATOMIC_RELAXED, __HIP_MEMORY_SCOPE_AGENT);
                v2 = __hip_atomic_load(gp + 1024, __ATOMIC_RELAXED, __HIP_MEMORY_SCOPE_AGENT);
                v3 = __hip_atomic_load(gp + 1536, __ATOMIC_RELAXED, __HIP_MEMORY_SCOPE_AGENT);
                if ((v0 != POISON) & (v1 != POISON) & (v2 != POISON) & (v3 != POISON)) break;
            }
            float gi = fsig(u2f(v0));
            float gf = fsig(u2f(v1));
            float gg = ftanh(u2f(v2));
            float go = fsig(u2f(v3));
            c = gf * c + gi * gg;
            float h = go * ftanh(c);
            h_s[tid] = h;
            if (wg == 0) {
                int tp = dir ? (TT - s) : (s - 1);
                hout[(size_t)tp * (2 * HH) + dir * HH + tid] = h;
            }
        } else {
            h_s[tid] = 0.f;
        }
        if (s == TT) break;

        // prefetch gx for step s+2 (lands long before its use)
        if (cch == 0) {
            gxf = 0.f;
            if (s + 2 < TT) {
                int tf = dir ? (TT - 3 - s) : (s + 2);
                gxf = gxd[(size_t)tf * G4H + grow];
            }
        }
        __syncthreads();                             // B2: h_s ready

        // dot: gate row `grow` x h_prev; 4 parallel accumulators
        float a0 = 0.f, a1 = 0.f, a2 = 0.f, a3 = 0.f;
        const float4* h4 = (const float4*)h_s;
        #pragma unroll
        for (int i = 0; i < 16; i += 4) {
            float4 p0 = h4[cch + 8 * (i + 0)];
            float4 p1 = h4[cch + 8 * (i + 1)];
            float4 p2 = h4[cch + 8 * (i + 2)];
            float4 p3 = h4[cch + 8 * (i + 3)];
            a0 += w[i + 0].x * p0.x + w[i + 0].y * p0.y + w[i + 0].z * p0.z + w[i + 0].w * p0.w;
            a1 += w[i + 1].x * p1.x + w[i + 1].y * p1.y + w[i + 1].z * p1.z + w[i + 1].w * p1.w;
            a2 += w[i + 2].x * p2.x + w[i + 2].y * p2.y + w[i + 2].z * p2.z + w[i + 2].w * p2.w;
            a3 += w[i + 3].x * p3.x + w[i + 3].y * p3.y + w[i + 3].z * p3.z + w[i + 3].w * p3.w;
        }
        float acc = (a0 + a1) + (a2 + a3);
        acc += __shfl_xor(acc, 1);
        acc += __shfl_xor(acc, 2);
        acc += __shfl_xor(acc, 4);
        if (cch == 0)
            __hip_atomic_store(gbuf + (size_t)s * G4H + grow,
                               f2u(acc + gxc),
                               __ATOMIC_RELAXED, __HIP_MEMORY_SCOPE_AGENT);
        __syncthreads();                             // B3: h_s safe to overwrite
        gxc = gxn; gxn = gxf;
    }
}

// ---------------- Viterbi forward + backtrack (bp in LDS, feats prefetch) ----
__global__ void viterbi_kernel(const float* __restrict__ feats,
                               const float* __restrict__ trans,
                               int* __restrict__ out) {
    const int n = threadIdx.x;   // blockDim = 64 (one wave)
    __shared__ float fv_s[NTAG];
    __shared__ uint8_t bp_s[TT][NTAG];   // 51200 B
    float tr[NTAG];
    if (n < NTAG) {
        #pragma unroll
        for (int p = 0; p < NTAG; ++p) tr[p] = trans[n * NTAG + p];
    }
    float fv = (n == 0) ? 0.f : NEGV;
    float fcur = (n < NTAG) ? feats[n] : 0.f;
    for (int t = 0; t < TT; ++t) {
        float fnext = (n < NTAG && t + 1 < TT) ? feats[(t + 1) * NTAG + n] : 0.f;
        if (n < NTAG) fv_s[n] = fv;
        __syncthreads();
        if (n < NTAG) {
            float best = -INFINITY; int bb = 0;
            #pragma unroll
            for (int p = 0; p < NTAG; ++p) {
                float sc = fv_s[p] + tr[p];
                if (sc > best) { best = sc; bb = p; }   // first-max tie rule
            }
            bp_s[t][n] = (uint8_t)bb;
            fv = best + fcur;
        }
        fcur = fnext;
        __syncthreads();
    }
    if (n < NTAG) fv_s[n] = fv;
    __syncthreads();
    if (n == 0) {
        float best = -INFINITY; int tag = 0;
        for (int p = 0; p < NTAG; ++p)
            if (fv_s[p] > best) { best = fv_s[p]; tag = p; }
        for (int t = TT - 1; t >= 0; --t) {
            out[t] = tag;
            tag = bp_s[t][tag];
        }
    }
}

extern "C" void kernel_launch(void* const* d_in, const int* in_sizes, int n_in,
                              void* d_out, int out_size, void* d_ws, size_t ws_size,
                              hipStream_t stream) {
    const int*   sent      = (const int*)d_in[0];
    const float* emb       = (const float*)d_in[1];
    const float* w_ih_l0_f = (const float*)d_in[2];
    const float* w_hh_l0_f = (const float*)d_in[3];
    const float* b_ih_l0_f = (const float*)d_in[4];
    const float* b_hh_l0_f = (const float*)d_in[5];
    const float* w_ih_l0_b = (const float*)d_in[6];
    const float* w_hh_l0_b = (const float*)d_in[7];
    const float* b_ih_l0_b = (const float*)d_in[8];
    const float* b_hh_l0_b = (const float*)d_in[9];
    const float* w_ih_l1_f = (const float*)d_in[10];
    const float* w_hh_l1_f = (const float*)d_in[11];
    const float* b_ih_l1_f = (const float*)d_in[12];
    const float* b_hh_l1_f = (const float*)d_in[13];
    const float* w_ih_l1_b = (const float*)d_in[14];
    const float* w_hh_l1_b = (const float*)d_in[15];
    const float* b_ih_l1_b = (const float*)d_in[16];
    const float* b_hh_l1_b = (const float*)d_in[17];
    const float* w_tag     = (const float*)d_in[18];
    const float* b_tag     = (const float*)d_in[19];
    const float* trans     = (const float*)d_in[20];

    char* ws = (char*)d_ws;
    float* x     = (float*)(ws);                 // T*300   = 2,457,600 B
    float* gx    = (float*)(ws + 2457600);       // 2*T*4H  = 33,554,432 B
    float* gates = (float*)(ws + 36012032);      // 2*T*4H  = 33,554,432 B ([2][T][4H])
    float* h1    = (float*)(ws + 69566464);      // T*2H    = 8,388,608 B
    float* h2    = (float*)(ws + 77955072);      // T*2H    = 8,388,608 B
    float* feats = (float*)(ws + 86343680);      // T*25

    const int NGATES = 2 * TT * G4H;

    poison_kernel<<<2048, 256, 0, stream>>>((uint32_t*)gates, NGATES);

    embed_kernel<<<TT, 128, 0, stream>>>(sent, emb, x);

    dim3 g0(TT / BM, G4H / BN);
    gemm_abt<<<g0, 256, 0, stream>>>(x, EE, w_ih_l0_f, EE, b_ih_l0_f, b_hh_l0_f,
                                     gx, G4H, TT, G4H, EE);
    gemm_abt<<<g0, 256, 0, stream>>>(x, EE, w_ih_l0_b, EE, b_ih_l0_b, b_hh_l0_b,
                                     gx + (size_t)TT * G4H, G4H, TT, G4H, EE);
    lstm_kernel<<<64, 512, 0, stream>>>(gx, w_hh_l0_f, w_hh_l0_b, gates, h1);

    dim3 g1(TT / GM, G4H / GN);
    gemm128<<<g1, 256, 0, stream>>>(h1, 2 * HH, w_ih_l1_f, 2 * HH, b_ih_l1_f, b_hh_l1_f,
                                    gx, G4H, 2 * HH);
    gemm128<<<g1, 256, 0, stream>>>(h1, 2 * HH, w_ih_l1_b, 2 * HH, b_ih_l1_b, b_hh_l1_b,
                                    gx + (size_t)TT * G4H, G4H, 2 * HH);
    poison_kernel<<<2048, 256, 0, stream>>>((uint32_t*)gates, NGATES);
    lstm_kernel<<<64, 512, 0, stream>>>(gx, w_hh_l1_f, w_hh_l1_b, gates, h2);

    dim3 gf(TT / BM, 1);
    gemm_abt<<<gf, 256, 0, stream>>>(h2, 2 * HH, w_tag, 2 * HH, b_tag, nullptr,
                                     feats, NTAG, TT, NTAG, 2 * HH);

    viterbi_kernel<<<1, 64, 0, stream>>>(feats, trans, (int*)d_out);
}